// Round 8
// baseline (383.096 us; speedup 1.0000x reference)
//
#include <hip/hip_runtime.h>
#include <hip/hip_bf16.h>

#define D_MODEL 1024
#define NUM_HEADS 16
#define HEAD_DIM 64
#define BATCH 4
#define SEQ 2048
#define MROWS (BATCH * SEQ)

using f32x4  = __attribute__((ext_vector_type(4))) float;
using bf16x8 = __attribute__((ext_vector_type(8))) short;
using short4v = __attribute__((ext_vector_type(4))) short;

__device__ inline unsigned short f2bf(float f) {
    __hip_bfloat16 h = __float2bfloat16(f);
    return *reinterpret_cast<unsigned short*>(&h);
}

// async global->LDS, 16B per lane; lds base must be wave-uniform
__device__ inline void gld_lds16(const unsigned short* g, unsigned short* l) {
    __builtin_amdgcn_global_load_lds(
        (const __attribute__((address_space(1))) unsigned int*)g,
        (__attribute__((address_space(3))) unsigned int*)l, 16, 0, 0);
}

#define QSCALE 0.18033688011112042f   // 0.125 / ln(2)

// ---------------------------------------------------------------------------
// Build circulant weight matrices, B^T layout: Wt[n][k] = c[(n-k)&1023], bf16.
// Wq/bq (rows 0..1023) pre-scaled by QSCALE so attn can use exp2 directly.
// ---------------------------------------------------------------------------
__global__ __launch_bounds__(256) void build_w(
    const float* __restrict__ cq, const float* __restrict__ ck,
    const float* __restrict__ cv, const float* __restrict__ co,
    const float* __restrict__ bq, const float* __restrict__ bk,
    const float* __restrict__ bv, const float* __restrict__ bo,
    unsigned short* __restrict__ Wt, float* __restrict__ bias)
{
    const int n = blockIdx.x;
    const int sel = n >> 10, nl = n & 1023;
    const float* c  = sel == 0 ? cq : sel == 1 ? ck : sel == 2 ? cv : co;
    const float* bb = sel == 0 ? bq : sel == 1 ? bk : sel == 2 ? bv : bo;
    const float sc = (sel == 0) ? QSCALE : 1.0f;
    const int t = threadIdx.x;
    ushort4 o;
    o.x = f2bf(sc * c[(nl - (4*t + 0)) & 1023]);
    o.y = f2bf(sc * c[(nl - (4*t + 1)) & 1023]);
    o.z = f2bf(sc * c[(nl - (4*t + 2)) & 1023]);
    o.w = f2bf(sc * c[(nl - (4*t + 3)) & 1023]);
    ((ushort4*)(Wt + (size_t)n * 1024))[t] = o;
    if (t == 0) bias[n] = sc * bb[nl];
}

__global__ __launch_bounds__(256) void xcast(
    const float* __restrict__ x, unsigned short* __restrict__ xb)
{
    const size_t i = (size_t)blockIdx.x * 1024 + threadIdx.x * 4;
    float4 v = *(const float4*)(x + i);
    ushort4 o;
    o.x = f2bf(v.x); o.y = f2bf(v.y); o.z = f2bf(v.z); o.w = f2bf(v.w);
    *(ushort4*)(xb + i) = o;
}

// ---------------------------------------------------------------------------
// bf16 GEMM: C = A * W + bias. 128x128 tile, BK=64, XOR swizzle, gld_lds16.
// OUT_MODE 0: Q (pre-scaled weights) row-major; K row-major; V transposed
//             per (b,head).  OUT_MODE 1: fp32 out.
// ---------------------------------------------------------------------------
template <int OUT_MODE>
__global__ __launch_bounds__(256, 3) void gemm_circ(
    const unsigned short* __restrict__ A,
    const unsigned short* __restrict__ Bt,
    const float* __restrict__ bias,
    unsigned short* __restrict__ Qb, unsigned short* __restrict__ Kb,
    unsigned short* __restrict__ Vt, float* __restrict__ Cf)
{
    __shared__ unsigned short As[128 * 64];
    __shared__ unsigned short Bs[128 * 64];
    const int t = threadIdx.x;
    const int w = t >> 6, lane = t & 63;
    const int quad = lane >> 4, l16 = lane & 15;
    const int m0 = blockIdx.x * 128;
    const int n0 = blockIdx.y * 128;
    const int wm = (w & 1) * 64, wn = (w >> 1) * 64;

    f32x4 acc[4][4];
#pragma unroll
    for (int i = 0; i < 4; ++i)
#pragma unroll
        for (int j = 0; j < 4; ++j) acc[i][j] = (f32x4){0.f, 0.f, 0.f, 0.f};

    for (int k0 = 0; k0 < 1024; k0 += 64) {
        __syncthreads();
#pragma unroll
        for (int j = 0; j < 4; ++j) {
            const int s = j * 4 + w;
            const int i = s * 64 + lane;
            const int r = i >> 3;
            const int c = (i & 7) ^ (r & 7);
            gld_lds16(A  + (size_t)(m0 + r) * 1024 + k0 + c * 8, &As[s * 512]);
            gld_lds16(Bt + (size_t)(n0 + r) * 1024 + k0 + c * 8, &Bs[s * 512]);
        }
        __syncthreads();

#pragma unroll
        for (int kk = 0; kk < 2; ++kk) {
            bf16x8 af[4], bfr[4];
#pragma unroll
            for (int i = 0; i < 4; ++i) {
                const int r = wm + i * 16 + l16;
                const int slot = r * 8 + ((kk * 4 + quad) ^ (r & 7));
                af[i] = *(const bf16x8*)&As[slot * 8];
            }
#pragma unroll
            for (int j = 0; j < 4; ++j) {
                const int r = wn + j * 16 + l16;
                const int slot = r * 8 + ((kk * 4 + quad) ^ (r & 7));
                bfr[j] = *(const bf16x8*)&Bs[slot * 8];
            }
#pragma unroll
            for (int i = 0; i < 4; ++i)
#pragma unroll
                for (int j = 0; j < 4; ++j)
                    acc[i][j] = __builtin_amdgcn_mfma_f32_16x16x32_bf16(
                        af[i], bfr[j], acc[i][j], 0, 0, 0);
        }
    }

#pragma unroll
    for (int i = 0; i < 4; ++i) {
        const int gm = m0 + wm + i * 16 + quad * 4;
#pragma unroll
        for (int j = 0; j < 4; ++j) {
            const int gn = n0 + wn + j * 16 + l16;
            const float bv = bias[gn];
            if (OUT_MODE == 1) {
#pragma unroll
                for (int rr = 0; rr < 4; ++rr)
                    Cf[(size_t)(gm + rr) * 1024 + gn] = acc[i][j][rr] + bv;
            } else {
                const int sel = gn >> 10;
                if (sel == 0) {
#pragma unroll
                    for (int rr = 0; rr < 4; ++rr)
                        Qb[(size_t)(gm + rr) * 1024 + gn] = f2bf(acc[i][j][rr] + bv);
                } else if (sel == 1) {
                    const int col = gn & 1023;
#pragma unroll
                    for (int rr = 0; rr < 4; ++rr)
                        Kb[(size_t)(gm + rr) * 1024 + col] = f2bf(acc[i][j][rr] + bv);
                } else {
                    const int d = gn & 1023;
                    const int head = d >> 6, dl = d & 63;
                    const int b = gm >> 11, key = gm & 2047;
                    ushort4 vv;
                    vv.x = f2bf(acc[i][j][0] + bv);
                    vv.y = f2bf(acc[i][j][1] + bv);
                    vv.z = f2bf(acc[i][j][2] + bv);
                    vv.w = f2bf(acc[i][j][3] + bv);
                    *(ushort4*)&Vt[((size_t)((b * 16 + head) * 64 + dl)) * 2048 + key] = vv;
                }
            }
        }
    }
}

// ---------------------------------------------------------------------------
// MFMA attention v6: 128-q blocks (grid 1024 = 4 blocks/CU, 40KB LDS),
// 32 q/wave in 2 strips, split-pass P (16-row per-wave Ps -> 8KB),
// S^T = K Q^T orientation, packed P path, dbuf K/V, 1 barrier/iter,
// __builtin_amdgcn_exp2f, improved P swizzle (extra q>>3 bit: 2-way max).
// ---------------------------------------------------------------------------
union PUn { uint2 u2; short4v s4; };

__global__ __launch_bounds__(256, 4) void attn_mfma(
    const unsigned short* __restrict__ Qb, const unsigned short* __restrict__ Kb,
    const unsigned short* __restrict__ Vt, unsigned short* __restrict__ O)
{
    __shared__ unsigned short Ks[2][64 * 64];   // 16KB [buf][key][d] swizzled
    __shared__ unsigned short Vs[2][64 * 64];   // 16KB [buf][d][key] swizzled
    __shared__ unsigned short Ps[4][16 * 64];   // 8KB per-wave P strip [q16][k64]

    const int t = threadIdx.x;
    const int w = t >> 6, lane = t & 63;
    const int quad = lane >> 4, l16 = lane & 15;
    const int qh = quad >> 1, ql = quad & 1;
    const int b = blockIdx.z, head = blockIdx.y;
    const int qbase = blockIdx.x * 128 + w * 32;
    // P swizzle bits for row q=l16: low (l16&7) plus bit from l16>>3
    const int psw = (l16 & 7) ^ ((l16 >> 3) << 2);

    // Q fragments (B-operand of S^T = K Q^T): lane l16 = q col, regs = d
    bf16x8 qa[2][2];
#pragma unroll
    for (int s = 0; s < 2; ++s)
#pragma unroll
        for (int h = 0; h < 2; ++h) {
            size_t off = (size_t)(b * SEQ + qbase + s*16 + l16) * D_MODEL
                       + head * HEAD_DIM + h*32 + quad*8;
            qa[s][h] = *(const bf16x8*)(Qb + off);
        }

    f32x4 acc[2][4];
#pragma unroll
    for (int s = 0; s < 2; ++s)
#pragma unroll
        for (int dt = 0; dt < 4; ++dt) acc[s][dt] = (f32x4){0.f,0.f,0.f,0.f};
    float lp[2] = {0.f, 0.f};

    const size_t kbase  = (size_t)(b * SEQ) * D_MODEL + head * HEAD_DIM;
    const size_t vtbase = (size_t)((b * NUM_HEADS + head) * HEAD_DIM) * SEQ;
    unsigned short* Pw = Ps[w];

    // prologue: stage k-block 0 into buffer 0
#pragma unroll
    for (int j = 0; j < 2; ++j) {
        const int seg = j * 4 + w;
        const int i = seg * 64 + lane;
        const int r = i >> 3;
        const int c = (i & 7) ^ (r & 7);
        gld_lds16(Kb + kbase + (size_t)r * D_MODEL + c * 8, &Ks[0][seg * 512]);
        gld_lds16(Vt + vtbase + (size_t)r * SEQ + c * 8, &Vs[0][seg * 512]);
    }

    int ib = 0;
    for (int kb = 0; kb < SEQ; kb += 64, ib ^= 1) {
        __syncthreads();   // buf ib staged

        if (kb + 64 < SEQ) {
#pragma unroll
            for (int j = 0; j < 2; ++j) {
                const int seg = j * 4 + w;
                const int i = seg * 64 + lane;
                const int r = i >> 3;
                const int c = (i & 7) ^ (r & 7);
                gld_lds16(Kb + kbase + (size_t)(kb + 64 + r) * D_MODEL + c * 8,
                          &Ks[ib ^ 1][seg * 512]);
                gld_lds16(Vt + vtbase + (size_t)r * SEQ + kb + 64 + c * 8,
                          &Vs[ib ^ 1][seg * 512]);
            }
        }

        // K fragments (A-operand: lane l16 = key row, regs = d)
        bf16x8 kf[4][2];
#pragma unroll
        for (int kt = 0; kt < 4; ++kt) {
            const int r = kt * 16 + l16;
#pragma unroll
            for (int h = 0; h < 2; ++h) {
                const int c = (h * 4 + quad) ^ (r & 7);
                kf[kt][h] = *(const bf16x8*)&Ks[ib][(r * 8 + c) * 8];
            }
        }

        // two passes: per 16-q strip, QK -> exp2 -> P strip -> PV
#pragma unroll
        for (int p = 0; p < 2; ++p) {
            f32x4 st[4];
#pragma unroll
            for (int kt = 0; kt < 4; ++kt) st[kt] = (f32x4){0.f,0.f,0.f,0.f};
#pragma unroll
            for (int kt = 0; kt < 4; ++kt)
#pragma unroll
                for (int h = 0; h < 2; ++h)
                    st[kt] = __builtin_amdgcn_mfma_f32_16x16x32_bf16(
                        kf[kt][h], qa[p][h], st[kt], 0, 0, 0);

            unsigned short* qrow = &Pw[l16 * 64];   // strip row q = l16
#pragma unroll
            for (int kt = 0; kt < 4; ++kt) {
                // lane holds k = kt*16 + quad*4 + {0..3} for q = l16
                float p0 = __builtin_amdgcn_exp2f(st[kt][0]);
                float p1 = __builtin_amdgcn_exp2f(st[kt][1]);
                float p2 = __builtin_amdgcn_exp2f(st[kt][2]);
                float p3 = __builtin_amdgcn_exp2f(st[kt][3]);
                lp[p] += (p0 + p1) + (p2 + p3);
                __hip_bfloat162 lo = __float22bfloat162_rn(make_float2(p0, p1));
                __hip_bfloat162 hi = __float22bfloat162_rn(make_float2(p2, p3));
                PUn pu;
                pu.u2.x = *reinterpret_cast<unsigned int*>(&lo);
                pu.u2.y = *reinterpret_cast<unsigned int*>(&hi);
                const int chunk = (kt * 2 + qh) ^ psw;
                *(short4v*)&qrow[chunk * 8 + ql * 4] = pu.s4;
            }

            // order P stores before PV loads; lgkmcnt only (prefetch unaffected)
            __asm__ __volatile__("" ::: "memory");
            __builtin_amdgcn_s_waitcnt(0xC07F);
            __asm__ __volatile__("" ::: "memory");

#pragma unroll
            for (int kh = 0; kh < 2; ++kh) {
                const int cp = ((kh * 4 + quad) ^ psw);
                bf16x8 pf = *(const bf16x8*)&Pw[(l16 * 8 + cp) * 8];
#pragma unroll
                for (int dt = 0; dt < 4; ++dt) {
                    const int r = dt * 16 + l16;
                    const int cv = (kh * 4 + quad) ^ (r & 7);
                    bf16x8 vf = *(const bf16x8*)&Vs[ib][(r * 8 + cv) * 8];
                    acc[p][dt] = __builtin_amdgcn_mfma_f32_16x16x32_bf16(
                        pf, vf, acc[p][dt], 0, 0, 0);
                }
            }
        }
    }

    // complete row sums: lanes {l16, +16, +32, +48} hold disjoint k-partials
#pragma unroll
    for (int s = 0; s < 2; ++s) {
        lp[s] += __shfl_xor(lp[s], 16);
        lp[s] += __shfl_xor(lp[s], 32);
    }

#pragma unroll
    for (int s = 0; s < 2; ++s)
#pragma unroll
        for (int rr = 0; rr < 4; ++rr) {
            // denom for q-row quad*4+rr lives at lane (quad*4+rr)
            float denom = __shfl(lp[s], quad * 4 + rr);
            float inv = 1.0f / denom;
            int q = qbase + s*16 + quad*4 + rr;
            unsigned short* orow = O + (size_t)(b * SEQ + q) * D_MODEL + head * HEAD_DIM + l16;
#pragma unroll
            for (int dt = 0; dt < 4; ++dt) orow[dt*16] = f2bf(acc[s][dt][rr] * inv);
        }
}

extern "C" void kernel_launch(void* const* d_in, const int* in_sizes, int n_in,
                              void* d_out, int out_size, void* d_ws, size_t ws_size,
                              hipStream_t stream) {
    const float* x    = (const float*)d_in[0];
    const float* wq_c = (const float*)d_in[1];
    const float* wq_b = (const float*)d_in[2];
    const float* wk_c = (const float*)d_in[3];
    const float* wk_b = (const float*)d_in[4];
    const float* wv_c = (const float*)d_in[5];
    const float* wv_b = (const float*)d_in[6];
    const float* wo_c = (const float*)d_in[7];
    const float* wo_b = (const float*)d_in[8];
    float* out = (float*)d_out;

    char* ws = (char*)d_ws;
    unsigned short* Wt   = (unsigned short*)(ws);                        // 8 MB
    float*          bias = (float*)(ws + ((size_t)8  << 20));            // 16 KB
    unsigned short* xb   = (unsigned short*)(ws + ((size_t)10 << 20));   // 16 MB
    unsigned short* Qb   = (unsigned short*)(ws + ((size_t)26 << 20));   // 16 MB
    unsigned short* Kb   = (unsigned short*)(ws + ((size_t)42 << 20));   // 16 MB
    unsigned short* Vt   = (unsigned short*)(ws + ((size_t)58 << 20));   // 16 MB
    unsigned short* Ob   = (unsigned short*)(ws + ((size_t)74 << 20));   // 16 MB

    build_w<<<4096, 256, 0, stream>>>(wq_c, wk_c, wv_c, wo_c,
                                      wq_b, wk_b, wv_b, wo_b, Wt, bias);
    xcast<<<MROWS, 256, 0, stream>>>(x, xb);
    gemm_circ<0><<<dim3(64, 24), 256, 0, stream>>>(xb, Wt, bias, Qb, Kb, Vt, nullptr);
    attn_mfma<<<dim3(SEQ / 128, NUM_HEADS, BATCH), 256, 0, stream>>>(Qb, Kb, Vt, Ob);
    gemm_circ<1><<<dim3(64, 8), 256, 0, stream>>>(Ob, Wt + (size_t)3072 * 1024,
                                                  bias + 3072, nullptr, nullptr, nullptr, out);
}

// Round 9
// 269.848 us; speedup vs baseline: 1.4197x; 1.4197x over previous
//
#include <hip/hip_runtime.h>
#include <hip/hip_bf16.h>

#define D_MODEL 1024
#define NUM_HEADS 16
#define HEAD_DIM 64
#define BATCH 4
#define SEQ 2048
#define MROWS (BATCH * SEQ)

using f32x4  = __attribute__((ext_vector_type(4))) float;
using bf16x8 = __attribute__((ext_vector_type(8))) short;
using short4v = __attribute__((ext_vector_type(4))) short;

__device__ inline unsigned short f2bf(float f) {
    __hip_bfloat16 h = __float2bfloat16(f);
    return *reinterpret_cast<unsigned short*>(&h);
}

// async global->LDS, 16B per lane; lds base must be wave-uniform
__device__ inline void gld_lds16(const unsigned short* g, unsigned short* l) {
    __builtin_amdgcn_global_load_lds(
        (const __attribute__((address_space(1))) unsigned int*)g,
        (__attribute__((address_space(3))) unsigned int*)l, 16, 0, 0);
}

#define QSCALE 0.18033688011112042f   // 0.125 / ln(2)

// ---------------------------------------------------------------------------
// Build circulant weight matrices, B^T layout: Wt[n][k] = c[(n-k)&1023], bf16.
// Wq/bq (rows 0..1023) pre-scaled by QSCALE so attn can use exp2 directly.
// ---------------------------------------------------------------------------
__global__ __launch_bounds__(256) void build_w(
    const float* __restrict__ cq, const float* __restrict__ ck,
    const float* __restrict__ cv, const float* __restrict__ co,
    const float* __restrict__ bq, const float* __restrict__ bk,
    const float* __restrict__ bv, const float* __restrict__ bo,
    unsigned short* __restrict__ Wt, float* __restrict__ bias)
{
    const int n = blockIdx.x;
    const int sel = n >> 10, nl = n & 1023;
    const float* c  = sel == 0 ? cq : sel == 1 ? ck : sel == 2 ? cv : co;
    const float* bb = sel == 0 ? bq : sel == 1 ? bk : sel == 2 ? bv : bo;
    const float sc = (sel == 0) ? QSCALE : 1.0f;
    const int t = threadIdx.x;
    ushort4 o;
    o.x = f2bf(sc * c[(nl - (4*t + 0)) & 1023]);
    o.y = f2bf(sc * c[(nl - (4*t + 1)) & 1023]);
    o.z = f2bf(sc * c[(nl - (4*t + 2)) & 1023]);
    o.w = f2bf(sc * c[(nl - (4*t + 3)) & 1023]);
    ((ushort4*)(Wt + (size_t)n * 1024))[t] = o;
    if (t == 0) bias[n] = sc * bb[nl];
}

__global__ __launch_bounds__(256) void xcast(
    const float* __restrict__ x, unsigned short* __restrict__ xb)
{
    const size_t i = (size_t)blockIdx.x * 1024 + threadIdx.x * 4;
    float4 v = *(const float4*)(x + i);
    ushort4 o;
    o.x = f2bf(v.x); o.y = f2bf(v.y); o.z = f2bf(v.z); o.w = f2bf(v.w);
    *(ushort4*)(xb + i) = o;
}

// ---------------------------------------------------------------------------
// bf16 GEMM: C = A * W + bias. 128x128 tile, BK=64, XOR swizzle, gld_lds16.
// OUT_MODE 0: Q (pre-scaled weights) row-major; K row-major; V transposed
//             per (b,head).  OUT_MODE 1: fp32 out.
// ---------------------------------------------------------------------------
template <int OUT_MODE>
__global__ __launch_bounds__(256, 3) void gemm_circ(
    const unsigned short* __restrict__ A,
    const unsigned short* __restrict__ Bt,
    const float* __restrict__ bias,
    unsigned short* __restrict__ Qb, unsigned short* __restrict__ Kb,
    unsigned short* __restrict__ Vt, float* __restrict__ Cf)
{
    __shared__ unsigned short As[128 * 64];
    __shared__ unsigned short Bs[128 * 64];
    const int t = threadIdx.x;
    const int w = t >> 6, lane = t & 63;
    const int quad = lane >> 4, l16 = lane & 15;
    const int m0 = blockIdx.x * 128;
    const int n0 = blockIdx.y * 128;
    const int wm = (w & 1) * 64, wn = (w >> 1) * 64;

    f32x4 acc[4][4];
#pragma unroll
    for (int i = 0; i < 4; ++i)
#pragma unroll
        for (int j = 0; j < 4; ++j) acc[i][j] = (f32x4){0.f, 0.f, 0.f, 0.f};

    for (int k0 = 0; k0 < 1024; k0 += 64) {
        __syncthreads();
#pragma unroll
        for (int j = 0; j < 4; ++j) {
            const int s = j * 4 + w;
            const int i = s * 64 + lane;
            const int r = i >> 3;
            const int c = (i & 7) ^ (r & 7);
            gld_lds16(A  + (size_t)(m0 + r) * 1024 + k0 + c * 8, &As[s * 512]);
            gld_lds16(Bt + (size_t)(n0 + r) * 1024 + k0 + c * 8, &Bs[s * 512]);
        }
        __syncthreads();

#pragma unroll
        for (int kk = 0; kk < 2; ++kk) {
            bf16x8 af[4], bfr[4];
#pragma unroll
            for (int i = 0; i < 4; ++i) {
                const int r = wm + i * 16 + l16;
                const int slot = r * 8 + ((kk * 4 + quad) ^ (r & 7));
                af[i] = *(const bf16x8*)&As[slot * 8];
            }
#pragma unroll
            for (int j = 0; j < 4; ++j) {
                const int r = wn + j * 16 + l16;
                const int slot = r * 8 + ((kk * 4 + quad) ^ (r & 7));
                bfr[j] = *(const bf16x8*)&Bs[slot * 8];
            }
#pragma unroll
            for (int i = 0; i < 4; ++i)
#pragma unroll
                for (int j = 0; j < 4; ++j)
                    acc[i][j] = __builtin_amdgcn_mfma_f32_16x16x32_bf16(
                        af[i], bfr[j], acc[i][j], 0, 0, 0);
        }
    }

#pragma unroll
    for (int i = 0; i < 4; ++i) {
        const int gm = m0 + wm + i * 16 + quad * 4;
#pragma unroll
        for (int j = 0; j < 4; ++j) {
            const int gn = n0 + wn + j * 16 + l16;
            const float bv = bias[gn];
            if (OUT_MODE == 1) {
#pragma unroll
                for (int rr = 0; rr < 4; ++rr)
                    Cf[(size_t)(gm + rr) * 1024 + gn] = acc[i][j][rr] + bv;
            } else {
                const int sel = gn >> 10;
                if (sel == 0) {
#pragma unroll
                    for (int rr = 0; rr < 4; ++rr)
                        Qb[(size_t)(gm + rr) * 1024 + gn] = f2bf(acc[i][j][rr] + bv);
                } else if (sel == 1) {
                    const int col = gn & 1023;
#pragma unroll
                    for (int rr = 0; rr < 4; ++rr)
                        Kb[(size_t)(gm + rr) * 1024 + col] = f2bf(acc[i][j][rr] + bv);
                } else {
                    const int d = gn & 1023;
                    const int head = d >> 6, dl = d & 63;
                    const int b = gm >> 11, key = gm & 2047;
                    ushort4 vv;
                    vv.x = f2bf(acc[i][j][0] + bv);
                    vv.y = f2bf(acc[i][j][1] + bv);
                    vv.z = f2bf(acc[i][j][2] + bv);
                    vv.w = f2bf(acc[i][j][3] + bv);
                    *(ushort4*)&Vt[((size_t)((b * 16 + head) * 64 + dl)) * 2048 + key] = vv;
                }
            }
        }
    }
}

// ---------------------------------------------------------------------------
// MFMA attention v7 = v5 (R7, verified) + builtin exp2 + XCD-aware grid:
// blockIdx.x = (b,head) [FAST axis -> round-robin over XCDs -> each XCD's 8
// resident (b,h) sets = 4MB K/V = its L2], blockIdx.y = q-tile [slow ->
// q-tiles of one (b,h) revisit the same XCD's warm L2].
// 256 q/block, 64 q/wave, dbuf K/V, 1 barrier/iter, S^T=KQ^T packed P path.
// ---------------------------------------------------------------------------
union PUn { uint2 u2; short4v s4; };

__global__ __launch_bounds__(256, 2) void attn_mfma(
    const unsigned short* __restrict__ Qb, const unsigned short* __restrict__ Kb,
    const unsigned short* __restrict__ Vt, unsigned short* __restrict__ O)
{
    __shared__ unsigned short Ks[2][64 * 64];   // [buf][key][d] swizzled
    __shared__ unsigned short Vs[2][64 * 64];   // [buf][d][key] swizzled
    __shared__ unsigned short Ps[4][64 * 64];   // per-wave P [q][k] swizzled

    const int t = threadIdx.x;
    const int w = t >> 6, lane = t & 63;
    const int quad = lane >> 4, l16 = lane & 15;
    const int qh = quad >> 1, ql = quad & 1;    // for packed P writes
    const int bh = blockIdx.x;                  // fast axis: (b,head)
    const int b = bh >> 4, head = bh & 15;
    const int qbase = blockIdx.y * 256 + w * 64;

    // Q fragments (B-operand of S^T = K Q^T): lane l16 = q-col, regs = d.
    bf16x8 qa[4][2];
#pragma unroll
    for (int s = 0; s < 4; ++s)
#pragma unroll
        for (int h = 0; h < 2; ++h) {
            size_t off = (size_t)(b * SEQ + qbase + s*16 + l16) * D_MODEL
                       + head * HEAD_DIM + h*32 + quad*8;
            qa[s][h] = *(const bf16x8*)(Qb + off);
        }

    f32x4 acc[4][4];   // [strip][d-tile], C-layout row=q, col=d
#pragma unroll
    for (int s = 0; s < 4; ++s)
#pragma unroll
        for (int dt = 0; dt < 4; ++dt) acc[s][dt] = (f32x4){0.f,0.f,0.f,0.f};
    float lp[4] = {0.f, 0.f, 0.f, 0.f};  // per-lane partial row sum, q = s*16+l16

    const size_t kbase  = (size_t)(b * SEQ) * D_MODEL + head * HEAD_DIM;
    const size_t vtbase = (size_t)((b * NUM_HEADS + head) * HEAD_DIM) * SEQ;
    unsigned short* Pw = Ps[w];

    // prologue: stage k-block 0 into buffer 0
#pragma unroll
    for (int j = 0; j < 2; ++j) {
        const int seg = j * 4 + w;
        const int i = seg * 64 + lane;
        const int r = i >> 3;
        const int c = (i & 7) ^ (r & 7);
        gld_lds16(Kb + kbase + (size_t)r * D_MODEL + c * 8, &Ks[0][seg * 512]);
        gld_lds16(Vt + vtbase + (size_t)r * SEQ + c * 8, &Vs[0][seg * 512]);
    }

    int ib = 0;
    for (int kb = 0; kb < SEQ; kb += 64, ib ^= 1) {
        __syncthreads();   // buf ib staged

        if (kb + 64 < SEQ) {
#pragma unroll
            for (int j = 0; j < 2; ++j) {
                const int seg = j * 4 + w;
                const int i = seg * 64 + lane;
                const int r = i >> 3;
                const int c = (i & 7) ^ (r & 7);
                gld_lds16(Kb + kbase + (size_t)(kb + 64 + r) * D_MODEL + c * 8,
                          &Ks[ib ^ 1][seg * 512]);
                gld_lds16(Vt + vtbase + (size_t)r * SEQ + kb + 64 + c * 8,
                          &Vs[ib ^ 1][seg * 512]);
            }
        }

        // K fragments (A-operand: lane l16 = key row, regs = d)
        bf16x8 kf[4][2];
#pragma unroll
        for (int kt = 0; kt < 4; ++kt) {
            const int r = kt * 16 + l16;
#pragma unroll
            for (int h = 0; h < 2; ++h) {
                const int c = (h * 4 + quad) ^ (r & 7);
                kf[kt][h] = *(const bf16x8*)&Ks[ib][(r * 8 + c) * 8];
            }
        }

        // per strip: S^T = K Q^T; p = exp2(S^T); packed b64 P writes
#pragma unroll
        for (int s = 0; s < 4; ++s) {
            f32x4 st[4];
#pragma unroll
            for (int kt = 0; kt < 4; ++kt) st[kt] = (f32x4){0.f,0.f,0.f,0.f};
#pragma unroll
            for (int kt = 0; kt < 4; ++kt)
#pragma unroll
                for (int h = 0; h < 2; ++h)
                    st[kt] = __builtin_amdgcn_mfma_f32_16x16x32_bf16(
                        kf[kt][h], qa[s][h], st[kt], 0, 0, 0);

            const int q = s * 16 + l16;
            unsigned short* qrow = &Pw[q * 64];   // logical row (swizzled chunks)
#pragma unroll
            for (int kt = 0; kt < 4; ++kt) {
                // lane holds k = kt*16 + quad*4 + {0..3} for q = s*16+l16
                float p0 = __builtin_amdgcn_exp2f(st[kt][0]);
                float p1 = __builtin_amdgcn_exp2f(st[kt][1]);
                float p2 = __builtin_amdgcn_exp2f(st[kt][2]);
                float p3 = __builtin_amdgcn_exp2f(st[kt][3]);
                lp[s] += (p0 + p1) + (p2 + p3);
                __hip_bfloat162 lo = __float22bfloat162_rn(make_float2(p0, p1));
                __hip_bfloat162 hi = __float22bfloat162_rn(make_float2(p2, p3));
                PUn pu;
                pu.u2.x = *reinterpret_cast<unsigned int*>(&lo);
                pu.u2.y = *reinterpret_cast<unsigned int*>(&hi);
                const int chunk = (kt * 2 + qh) ^ (q & 7);
                *(short4v*)&qrow[chunk * 8 + ql * 4] = pu.s4;
            }
        }

        // Order P stores before PV loads: compiler barrier + lgkmcnt(0) only
        // (0xC07F = vmcnt(63) expcnt(7) lgkmcnt(0) -> K/V prefetch unaffected).
        __asm__ __volatile__("" ::: "memory");
        __builtin_amdgcn_s_waitcnt(0xC07F);
        __asm__ __volatile__("" ::: "memory");

        // O += P V  (pf per strip, vf shared across strips)
#pragma unroll
        for (int kh = 0; kh < 2; ++kh) {
            bf16x8 pf[4];
#pragma unroll
            for (int s = 0; s < 4; ++s) {
                const int q = s * 16 + l16;
                const int c = (kh * 4 + quad) ^ (q & 7);
                pf[s] = *(const bf16x8*)&Pw[(q * 8 + c) * 8];
            }
#pragma unroll
            for (int dt = 0; dt < 4; ++dt) {
                const int r = dt * 16 + l16;
                const int cv = (kh * 4 + quad) ^ (r & 7);
                bf16x8 vf = *(const bf16x8*)&Vs[ib][(r * 8 + cv) * 8];
#pragma unroll
                for (int s = 0; s < 4; ++s)
                    acc[s][dt] = __builtin_amdgcn_mfma_f32_16x16x32_bf16(
                        pf[s], vf, acc[s][dt], 0, 0, 0);
            }
        }
    }

    // complete row sums: lanes {l16, +16, +32, +48} hold disjoint k-partials
#pragma unroll
    for (int s = 0; s < 4; ++s) {
        lp[s] += __shfl_xor(lp[s], 16);
        lp[s] += __shfl_xor(lp[s], 32);
    }

#pragma unroll
    for (int s = 0; s < 4; ++s)
#pragma unroll
        for (int rr = 0; rr < 4; ++rr) {
            // denom for q = s*16 + quad*4 + rr lives at lane (quad*4+rr)
            float denom = __shfl(lp[s], quad * 4 + rr);
            float inv = 1.0f / denom;
            int q = qbase + s*16 + quad*4 + rr;
            unsigned short* orow = O + (size_t)(b * SEQ + q) * D_MODEL + head * HEAD_DIM + l16;
#pragma unroll
            for (int dt = 0; dt < 4; ++dt) orow[dt*16] = f2bf(acc[s][dt][rr] * inv);
        }
}

extern "C" void kernel_launch(void* const* d_in, const int* in_sizes, int n_in,
                              void* d_out, int out_size, void* d_ws, size_t ws_size,
                              hipStream_t stream) {
    const float* x    = (const float*)d_in[0];
    const float* wq_c = (const float*)d_in[1];
    const float* wq_b = (const float*)d_in[2];
    const float* wk_c = (const float*)d_in[3];
    const float* wk_b = (const float*)d_in[4];
    const float* wv_c = (const float*)d_in[5];
    const float* wv_b = (const float*)d_in[6];
    const float* wo_c = (const float*)d_in[7];
    const float* wo_b = (const float*)d_in[8];
    float* out = (float*)d_out;

    char* ws = (char*)d_ws;
    unsigned short* Wt   = (unsigned short*)(ws);                        // 8 MB
    float*          bias = (float*)(ws + ((size_t)8  << 20));            // 16 KB
    unsigned short* xb   = (unsigned short*)(ws + ((size_t)10 << 20));   // 16 MB
    unsigned short* Qb   = (unsigned short*)(ws + ((size_t)26 << 20));   // 16 MB
    unsigned short* Kb   = (unsigned short*)(ws + ((size_t)42 << 20));   // 16 MB
    unsigned short* Vt   = (unsigned short*)(ws + ((size_t)58 << 20));   // 16 MB
    unsigned short* Ob   = (unsigned short*)(ws + ((size_t)74 << 20));   // 16 MB

    build_w<<<4096, 256, 0, stream>>>(wq_c, wk_c, wv_c, wo_c,
                                      wq_b, wk_b, wv_b, wo_b, Wt, bias);
    xcast<<<MROWS, 256, 0, stream>>>(x, xb);
    gemm_circ<0><<<dim3(64, 24), 256, 0, stream>>>(xb, Wt, bias, Qb, Kb, Vt, nullptr);
    // fast axis = (b,head): round-robin over XCDs; q-tiles (slow) revisit warm L2
    attn_mfma<<<dim3(BATCH * NUM_HEADS, SEQ / 256), 256, 0, stream>>>(Qb, Kb, Vt, Ob);
    gemm_circ<1><<<dim3(64, 8), 256, 0, stream>>>(Ob, Wt + (size_t)3072 * 1024,
                                                  bias + 3072, nullptr, nullptr, nullptr, out);
}